// Round 1
// baseline (676.921 us; speedup 1.0000x reference)
//
#include <hip/hip_runtime.h>

// LabelSmoothing: x [N=4096, V=32000] fp32 logprobs, target [N] int.
//   mask = target != 0
//   loss = -sum(x * mask[:,None]);  nll = -sum(x[i, target[i]] * mask)
//   out  = 0.1 * loss / V + 0.9 * nll          (single fp32 scalar)
//
// Memory-bound: 524 MB streaming read. One block per row (128 KB contiguous,
// float4-coalesced), wave64 shuffle reduce -> LDS -> 1 atomicAdd per block.

#define LS_V 32000
#define LS_V4 8000          // float4 per row
#define LS_SMOOTH 0.1f

__global__ __launch_bounds__(256) void ls_row_reduce(
    const float* __restrict__ x,
    const int*   __restrict__ target,
    float*       __restrict__ out)
{
    const int row = blockIdx.x;
    const int tid = threadIdx.x;

    const int t = target[row];          // scalar broadcast load
    const bool valid = (t != 0);        // PADDING_IDX == 0

    float s = 0.0f;
    if (valid) {
        const float4* __restrict__ xr =
            (const float4*)(x + (size_t)row * LS_V);
        // 8000 float4 per row, 256 threads -> 31..32 iters each, coalesced.
        for (int j = tid; j < LS_V4; j += 256) {
            float4 v = xr[j];
            s += (v.x + v.y) + (v.z + v.w);
        }
    }

    // wave64 butterfly-free down-reduce
    #pragma unroll
    for (int off = 32; off > 0; off >>= 1)
        s += __shfl_down(s, off, 64);

    __shared__ float wsum[4];           // 256 threads = 4 waves
    const int lane = tid & 63;
    const int wave = tid >> 6;
    if (lane == 0) wsum[wave] = s;
    __syncthreads();

    if (tid == 0) {
        const float S = (wsum[0] + wsum[1]) + (wsum[2] + wsum[3]);
        // gather term: row already streamed by this block -> L1/L2 hit
        const float g = valid ? x[(size_t)row * LS_V + t] : 0.0f;
        // per-row contribution:
        //   0.1 * (-S)/V + 0.9 * (-g)
        const float contrib = -(LS_SMOOTH / (float)LS_V) * S
                              - (1.0f - LS_SMOOTH) * g;
        atomicAdd(out, contrib);        // device-scope by default on CDNA
    }
}

extern "C" void kernel_launch(void* const* d_in, const int* in_sizes, int n_in,
                              void* d_out, int out_size, void* d_ws, size_t ws_size,
                              hipStream_t stream)
{
    const float* x      = (const float*)d_in[0];   // [4096, 32000] fp32
    const int*   target = (const int*)d_in[1];     // [4096] int
    float*       out    = (float*)d_out;           // scalar fp32

    const int N = in_sizes[1];                     // 4096 rows

    // d_out is re-poisoned to 0xAA before every timed launch -> zero it.
    hipMemsetAsync(out, 0, sizeof(float), stream);

    ls_row_reduce<<<N, 256, 0, stream>>>(x, target, out);
}

// Round 3
// 628.765 us; speedup vs baseline: 1.0766x; 1.0766x over previous
//
#include <hip/hip_runtime.h>

// LabelSmoothing: x [N=4096, V=32000] fp32, target [N] int.
//   out = 0.1 * (-sum(x[valid rows])) / V + 0.9 * (-sum(x[i, target[i]], valid))
//
// Memory-bound streaming reduce (524 MB read once).
// Kernel 1: one block per row, 2x float4 nontemporal streams, 2 accumulators,
//           per-row partial contribution written to d_ws (no atomics, no memset).
// Kernel 2: single block reduces 4096 partials -> d_out scalar.

#define LS_V 32000
#define LS_V4 8000          // float4 per row
#define LS_SMOOTH 0.1f

// __builtin_nontemporal_load requires a native Clang vector type,
// not HIP's HIP_vector_type<float,4> class.
typedef float f4 __attribute__((ext_vector_type(4)));

__global__ __launch_bounds__(256) void ls_row_reduce(
    const float* __restrict__ x,
    const int*   __restrict__ target,
    float*       __restrict__ partial)
{
    const int row = blockIdx.x;
    const int tid = threadIdx.x;

    const int t = target[row];          // scalar broadcast load
    const bool valid = (t != 0);        // PADDING_IDX == 0

    float s0 = 0.0f, s1 = 0.0f;
    if (valid) {
        const f4* __restrict__ xr =
            (const f4*)(x + (size_t)row * LS_V);
        // 8000 float4 = 15 * 512 + 320. Two independent streams per thread:
        // j and j+256, separate accumulators to break the FP dep chain.
        int j = tid;
        #pragma unroll 5
        for (int i = 0; i < 15; ++i, j += 512) {
            f4 a = __builtin_nontemporal_load(&xr[j]);
            f4 b = __builtin_nontemporal_load(&xr[j + 256]);
            s0 += (a.x + a.y) + (a.z + a.w);
            s1 += (b.x + b.y) + (b.z + b.w);
        }
        // tail: 320 float4 remain. j == tid + 7680 here.
        {
            f4 a = __builtin_nontemporal_load(&xr[j]);          // 7680..7935
            s0 += (a.x + a.y) + (a.z + a.w);
            if (tid < 64) {
                f4 b = __builtin_nontemporal_load(&xr[j + 256]); // 7936..7999
                s1 += (b.x + b.y) + (b.z + b.w);
            }
        }
    }

    float s = s0 + s1;
    #pragma unroll
    for (int off = 32; off > 0; off >>= 1)
        s += __shfl_down(s, off, 64);

    __shared__ float wsum[4];           // 256 threads = 4 waves
    if ((tid & 63) == 0) wsum[tid >> 6] = s;
    __syncthreads();

    if (tid == 0) {
        const float S = (wsum[0] + wsum[1]) + (wsum[2] + wsum[3]);
        // gather term: likely still L2-resident from this block's stream
        const float g = valid ? x[(size_t)row * LS_V + t] : 0.0f;
        partial[row] = -(LS_SMOOTH / (float)LS_V) * S
                       - (1.0f - LS_SMOOTH) * g;
    }
}

__global__ __launch_bounds__(256) void ls_final(
    const float* __restrict__ partial,
    float*       __restrict__ out,
    int n)
{
    const int tid = threadIdx.x;
    float s = 0.0f;
    for (int i = tid; i < n; i += 256) s += partial[i];

    #pragma unroll
    for (int off = 32; off > 0; off >>= 1)
        s += __shfl_down(s, off, 64);

    __shared__ float wsum[4];
    if ((tid & 63) == 0) wsum[tid >> 6] = s;
    __syncthreads();
    if (tid == 0) out[0] = (wsum[0] + wsum[1]) + (wsum[2] + wsum[3]);
}

extern "C" void kernel_launch(void* const* d_in, const int* in_sizes, int n_in,
                              void* d_out, int out_size, void* d_ws, size_t ws_size,
                              hipStream_t stream)
{
    const float* x      = (const float*)d_in[0];   // [4096, 32000] fp32
    const int*   target = (const int*)d_in[1];     // [4096] int
    float*       out    = (float*)d_out;           // scalar fp32
    float*       part   = (float*)d_ws;            // 4096 fp32 partials

    const int N = in_sizes[1];                     // 4096 rows

    ls_row_reduce<<<N, 256, 0, stream>>>(x, target, part);
    ls_final<<<1, 256, 0, stream>>>(part, out, N);
}

// Round 4
// 627.593 us; speedup vs baseline: 1.0786x; 1.0019x over previous
//
#include <hip/hip_runtime.h>

// LabelSmoothing: x [N=4096, V=32000] fp32, target [N] int.
//   out = 0.1 * (-sum(x[valid rows])) / V + 0.9 * (-sum(x[i, target[i]], valid))
//
// Memory-bound streaming reduce (524 MB read once). One block per row.
// R4 changes vs R3:
//  - stream the row UNCONDITIONALLY (no data-dependent guard on target load);
//    apply the padding mask multiplicatively at the end. Removes the
//    target-load -> row-stream serialization at every block start.
//  - issue the gather x[row, t] at the TOP of the kernel (wave-broadcast, one
//    transaction) so its HBM latency overlaps the streaming loop instead of
//    stalling thread 0 after the barrier (nt loads don't retain the line).

#define LS_V 32000
#define LS_V4 8000          // float4 per row
#define LS_SMOOTH 0.1f

// __builtin_nontemporal_load requires a native Clang vector type.
typedef float f4 __attribute__((ext_vector_type(4)));

__global__ __launch_bounds__(256) void ls_row_reduce(
    const float* __restrict__ x,
    const int*   __restrict__ target,
    float*       __restrict__ partial)
{
    const int row = blockIdx.x;
    const int tid = threadIdx.x;

    const int t = target[row];                 // scalar broadcast load
    // Early gather: always in-bounds (t in [0,V)), whole wave hits one line.
    const float g = x[(size_t)row * LS_V + t];

    const f4* __restrict__ xr = (const f4*)(x + (size_t)row * LS_V);

    // 8000 float4 = 15 * 512 + 320. Two independent streams per thread.
    float s0 = 0.0f, s1 = 0.0f;
    int j = tid;
    #pragma unroll 5
    for (int i = 0; i < 15; ++i, j += 512) {
        f4 a = __builtin_nontemporal_load(&xr[j]);
        f4 b = __builtin_nontemporal_load(&xr[j + 256]);
        s0 += (a.x + a.y) + (a.z + a.w);
        s1 += (b.x + b.y) + (b.z + b.w);
    }
    // tail: 320 float4 remain; j == tid + 7680 here.
    {
        f4 a = __builtin_nontemporal_load(&xr[j]);               // 7680..7935
        s0 += (a.x + a.y) + (a.z + a.w);
        if (tid < 64) {
            f4 b = __builtin_nontemporal_load(&xr[j + 256]);     // 7936..7999
            s1 += (b.x + b.y) + (b.z + b.w);
        }
    }

    float s = s0 + s1;
    #pragma unroll
    for (int off = 32; off > 0; off >>= 1)
        s += __shfl_down(s, off, 64);

    __shared__ float wsum[4];                  // 256 threads = 4 waves
    if ((tid & 63) == 0) wsum[tid >> 6] = s;
    __syncthreads();

    if (tid == 0) {
        const float S = (wsum[0] + wsum[1]) + (wsum[2] + wsum[3]);
        const float maskf = (t != 0) ? 1.0f : 0.0f;   // PADDING_IDX == 0
        partial[row] = maskf * (-(LS_SMOOTH / (float)LS_V) * S
                                - (1.0f - LS_SMOOTH) * g);
    }
}

__global__ __launch_bounds__(256) void ls_final(
    const float* __restrict__ partial,
    float*       __restrict__ out,
    int n)
{
    const int tid = threadIdx.x;
    float s = 0.0f;
    for (int i = tid; i < n; i += 256) s += partial[i];

    #pragma unroll
    for (int off = 32; off > 0; off >>= 1)
        s += __shfl_down(s, off, 64);

    __shared__ float wsum[4];
    if ((tid & 63) == 0) wsum[tid >> 6] = s;
    __syncthreads();
    if (tid == 0) out[0] = (wsum[0] + wsum[1]) + (wsum[2] + wsum[3]);
}

extern "C" void kernel_launch(void* const* d_in, const int* in_sizes, int n_in,
                              void* d_out, int out_size, void* d_ws, size_t ws_size,
                              hipStream_t stream)
{
    const float* x      = (const float*)d_in[0];   // [4096, 32000] fp32
    const int*   target = (const int*)d_in[1];     // [4096] int
    float*       out    = (float*)d_out;           // scalar fp32
    float*       part   = (float*)d_ws;            // 4096 fp32 partials

    const int N = in_sizes[1];                     // 4096 rows

    ls_row_reduce<<<N, 256, 0, stream>>>(x, target, part);
    ls_final<<<1, 256, 0, stream>>>(part, out, N);
}